// Round 2
// baseline (717.690 us; speedup 1.0000x reference)
//
#include <hip/hip_runtime.h>
#include <hip/hip_bf16.h>
#include <stdint.h>

#define VOCABN 100000
#define EDIM 128
#define BN 16
#define SN 2048
#define VPB 128
#define NBV 782          // ceil(100000/128)

// ws float offsets
#define H_OFF    0        // 2048
#define U0_OFF   2048     // 2048
#define U1_OFF   4096     // 2048
#define DU_OFF   6144     // 2*2048 (du_raw[2][16][128])
#define PS_OFF   10240    // 128 (psum[16][8])
#define PBV_OFF  10368    // 1200
#define PBI_OFF  11568    // 1200
#define DT_OFF   16384    // 1,600,000 (D^T [100000][16])
#define WT_OFF   1616384  // 1,600,000 (wt [100000][16])

// ---------- threefry2x32 (JAX partitionable) ----------
__host__ __device__ inline void tf2x32(uint32_t k0, uint32_t k1,
                                       uint32_t x0, uint32_t x1,
                                       uint32_t* o0, uint32_t* o1) {
  const uint32_t rotA[4] = {13u, 15u, 26u, 6u};
  const uint32_t rotB[4] = {17u, 29u, 16u, 24u};
  uint32_t ks0 = k0, ks1 = k1, ks2 = k0 ^ k1 ^ 0x1BD11BDAu;
  x0 += ks0; x1 += ks1;
#pragma unroll
  for (int g = 0; g < 5; ++g) {
    const uint32_t* r = (g & 1) ? rotB : rotA;
#pragma unroll
    for (int i = 0; i < 4; ++i) {
      x0 += x1;
      x1 = (x1 << r[i]) | (x1 >> (32u - r[i]));
      x1 ^= x0;
    }
    uint32_t a0 = (g % 3 == 0) ? ks1 : ((g % 3 == 1) ? ks2 : ks0);
    uint32_t a1 = (g % 3 == 0) ? ks2 : ((g % 3 == 1) ? ks0 : ks1);
    x0 += a0;
    x1 += a1 + (uint32_t)(g + 1);
  }
  *o0 = x0; *o1 = x1;
}

__device__ inline float gumbel(uint32_t ka, uint32_t kb, uint32_t flat) {
  uint32_t o0, o1;
  tf2x32(ka, kb, 0u, flat, &o0, &o1);
  uint32_t bits = o0 ^ o1;
  float u0 = __uint_as_float((bits >> 9) | 0x3f800000u) - 1.0f;
  float uu = fmaxf(1e-10f, u0 + 1e-10f);
  return -logf(-logf(uu));
}

// ---------- h = hidden @ Wm^T + Wb ; u0 = h ----------
__global__ void k_h(const float* __restrict__ hidden, const float* __restrict__ Wm,
                    const float* __restrict__ Wb, float* __restrict__ h,
                    float* __restrict__ u) {
  int b = blockIdx.x, j = threadIdx.x;
  const float4* wr = (const float4*)(Wm + (size_t)j * EDIM);
  const float4* hr = (const float4*)(hidden + (size_t)b * EDIM);
  float acc = Wb[j];
#pragma unroll
  for (int i = 0; i < 32; ++i) {
    float4 w4 = wr[i], h4 = hr[i];
    acc += w4.x * h4.x + w4.y * h4.y + w4.z * h4.z + w4.w * h4.w;
  }
  h[b * EDIM + j] = acc;
  u[b * EDIM + j] = acc;
}

// ---------- heads: logits to out; per-chunk gumbel-argmax partials ----------
__global__ void k_heads(const float* __restrict__ h,
                        const float* __restrict__ W1w, const float* __restrict__ W1b,
                        const float* __restrict__ W3w, const float* __restrict__ W3b,
                        const float* __restrict__ W4w, const float* __restrict__ W4b,
                        float* __restrict__ out, float* __restrict__ pbv,
                        int* __restrict__ pbi,
                        uint32_t k0a, uint32_t k0b, uint32_t k1a, uint32_t k1b,
                        uint32_t k2a, uint32_t k2b) {
  int bid = blockIdx.x, tid = threadIdx.x;
  __shared__ float hb[EDIM];
  __shared__ float sv[256];
  __shared__ int si[256];
  int head, b2, base, cnt, chunk, N;
  const float *W, *bias; size_t lg_off; uint32_t ka, kb;
  if (bid < 400)      { head = 1; b2 = bid / 25; chunk = bid % 25; base = chunk * 160; cnt = 160;
                        W = W3w; bias = W3b; N = 4000; lg_off = 64;     ka = k1a; kb = k1b; }
  else if (bid < 416) { head = 2; b2 = bid - 400; chunk = 0; base = 0; cnt = 200;
                        W = W4w; bias = W4b; N = 200;  lg_off = 128064; ka = k2a; kb = k2b; }
  else                { head = 0; b2 = bid - 416; chunk = 0; base = 0; cnt = 2;
                        W = W1w; bias = W1b; N = 2;    lg_off = 0;      ka = k0a; kb = k0b; }
  if (tid < 128) hb[tid] = h[b2 * EDIM + tid];
  __syncthreads();
  float best = -INFINITY; int bi = 0x7FFFFFFF;
  if (tid < cnt) {
    int c = base + tid;
    const float4* wr = (const float4*)(W + (size_t)c * EDIM);
    const float4* hb4 = (const float4*)hb;
    float acc = bias[c];
#pragma unroll
    for (int i = 0; i < 32; ++i) {
      float4 w4 = wr[i], h4 = hb4[i];
      acc += w4.x * h4.x + w4.y * h4.y + w4.z * h4.z + w4.w * h4.w;
    }
    out[lg_off + (size_t)b2 * N + c] = acc;
    best = acc + gumbel(ka, kb, (uint32_t)(b2 * N + c));
    bi = c;
  }
  sv[tid] = best; si[tid] = bi;
  __syncthreads();
  for (int s2 = 128; s2 > 0; s2 >>= 1) {
    if (tid < s2) {
      float ov = sv[tid + s2]; int oi = si[tid + s2];
      if (ov > sv[tid] || (ov == sv[tid] && oi < si[tid])) { sv[tid] = ov; si[tid] = oi; }
    }
    __syncthreads();
  }
  if (tid == 0) {
    pbv[(head * 16 + b2) * 25 + chunk] = sv[0];
    pbi[(head * 16 + b2) * 25 + chunk] = si[0];
  }
}

// ---------- one-hots ----------
__global__ void k_onehot(const float* __restrict__ pbv, const int* __restrict__ pbi,
                         float* __restrict__ out) {
  int g = blockIdx.x * 256 + threadIdx.x;
  if (g >= 67232) return;
  int head, b2, c; size_t off; int nch;
  if (g < 64000)      { head = 1; b2 = g / 4000; c = g % 4000; off = 64064 + g;          nch = 25; }
  else if (g < 67200) { int gg = g - 64000; head = 2; b2 = gg / 200; c = gg % 200; off = 131264 + gg; nch = 1; }
  else                { int gg = g - 67200; head = 0; b2 = gg >> 1; c = gg & 1;   off = 32 + gg;     nch = 1; }
  float bv = -INFINITY; int bi = 0x7FFFFFFF;
  for (int ch = 0; ch < nch; ++ch) {
    float v = pbv[(head * 16 + b2) * 25 + ch];
    int i2 = pbi[(head * 16 + b2) * 25 + ch];
    if (v > bv || (v == bv && i2 < bi)) { bv = v; bi = i2; }
  }
  out[off] = (c == bi) ? 1.0f : 0.0f;
}

// ---------- k_D: stream table Ct; Dt[v][b] = Ct[v] . u_eff[b] ----------
// u_eff = u_in + (use_du ? du/S_b : 0), S_b from psum. Optionally zero wt/du
// stripes and persist u_eff to u_out (block 0 only).
__global__ void __launch_bounds__(256) k_D(const float* __restrict__ Ct,
                                           const float* __restrict__ u_in,
                                           const float* __restrict__ du,
                                           const float* __restrict__ ps,
                                           int use_du,
                                           float* __restrict__ u_out,
                                           float* __restrict__ Dt,
                                           float* __restrict__ wtz,
                                           float* __restrict__ duz) {
  __shared__ __align__(16) float u_s[16][132];
  __shared__ __align__(16) float r_s[16][132];
  const int bid = blockIdx.x, tid = threadIdx.x;

  if (wtz) {
    for (int i = bid * 256 + tid; i < VOCABN * 16; i += NBV * 256) wtz[i] = 0.f;
  }
  if (duz && bid == 0) {
    for (int i = tid; i < 4096; i += 256) duz[i] = 0.f;
  }

  // u_eff into LDS
  for (int i = tid; i < 2048; i += 256) {
    int b = i >> 7, e = i & 127;
    float v = u_in[i];
    if (use_du) {
      float S = 0.f;
#pragma unroll
      for (int sl = 0; sl < 8; ++sl) S += ps[b * 8 + sl];
      v += du[i] * (1.0f / S);
    }
    u_s[b][e] = v;
    if (u_out && bid == 0) u_out[i] = v;
  }

  const int v0 = bid * VPB;
  const int vl = tid >> 4, b = tid & 15;
  for (int r = 0; r < VPB / 16; ++r) {
    int vr0 = v0 + r * 16;
    __syncthreads();           // protect r_s from previous round readers (also covers u_s r=0)
    for (int i = tid; i < 512; i += 256) {
      int row = i >> 5, c4 = i & 31;
      float4 val = make_float4(0.f, 0.f, 0.f, 0.f);
      if (vr0 + row < VOCABN)
        val = ((const float4*)(Ct + (size_t)(vr0 + row) * EDIM))[c4];
      *(float4*)&r_s[row][c4 * 4] = val;
    }
    __syncthreads();
    float acc = 0.f;
    const float4* rr = (const float4*)&r_s[vl][0];
    const float4* uu = (const float4*)&u_s[b][0];
#pragma unroll
    for (int i = 0; i < 32; ++i) {
      float4 a = rr[i], c = uu[i];
      acc += a.x * c.x + a.y * c.y + a.z * c.z + a.w * c.w;
    }
    int v = vr0 + vl;
    if (v < VOCABN) Dt[(size_t)v * 16 + b] = acc;
  }
}

// ---------- k_lscat: l[b,s] = sum_m Dt[tok][b]; scatter exp(l) into wt; psum ----------
__global__ void __launch_bounds__(256) k_lscat(const int* __restrict__ story,
                                               const float* __restrict__ Dt,
                                               float* __restrict__ wt,
                                               float* __restrict__ ps) {
  const int bid = blockIdx.x, tid = threadIdx.x;
  const int b = bid >> 3, sl = bid & 7;
  const int s = sl * 256 + tid;
  const int wave = tid >> 6, lane = tid & 63;
  int4 tk = ((const int4*)story)[b * SN + s];
  float l = Dt[(size_t)tk.x * 16 + b] + Dt[(size_t)tk.y * 16 + b]
          + Dt[(size_t)tk.z * 16 + b] + Dt[(size_t)tk.w * 16 + b];
  float e = expf(l);
  atomicAdd(&wt[(size_t)tk.x * 16 + b], e);
  atomicAdd(&wt[(size_t)tk.y * 16 + b], e);
  atomicAdd(&wt[(size_t)tk.z * 16 + b], e);
  atomicAdd(&wt[(size_t)tk.w * 16 + b], e);
  // block-reduce e -> psum[b][sl]
  float sum = e;
#pragma unroll
  for (int off = 32; off > 0; off >>= 1) sum += __shfl_xor(sum, off, 64);
  __shared__ float red[4];
  if (lane == 0) red[wave] = sum;
  __syncthreads();
  if (tid == 0) ps[b * 8 + sl] = red[0] + red[1] + red[2] + red[3];
}

// ---------- k_du: du_raw[b][e] = sum_v wt[v][b] * Ct[v][e] (block partials + atomics) ----------
__global__ void __launch_bounds__(256) k_du(const float* __restrict__ Ct,
                                            const float* __restrict__ wt,
                                            float* __restrict__ du) {
  __shared__ __align__(16) float r_s[16][132];
  __shared__ float w_s[16][17];
  const int bid = blockIdx.x, tid = threadIdx.x;
  const int b = tid >> 4, e8 = (tid & 15) * 8;
  float acc[8] = {0.f, 0.f, 0.f, 0.f, 0.f, 0.f, 0.f, 0.f};
  const int v0 = bid * VPB;
  for (int r = 0; r < VPB / 16; ++r) {
    int vr0 = v0 + r * 16;
    __syncthreads();
    for (int i = tid; i < 512; i += 256) {
      int row = i >> 5, c4 = i & 31;
      float4 val = make_float4(0.f, 0.f, 0.f, 0.f);
      if (vr0 + row < VOCABN)
        val = ((const float4*)(Ct + (size_t)(vr0 + row) * EDIM))[c4];
      *(float4*)&r_s[row][c4 * 4] = val;
    }
    {
      int row = tid >> 4, bb = tid & 15;
      w_s[row][bb] = (vr0 + row < VOCABN) ? wt[(size_t)(vr0 + row) * 16 + bb] : 0.f;
    }
    __syncthreads();
#pragma unroll
    for (int v = 0; v < 16; ++v) {
      float w = w_s[v][b];
      const float4* rp = (const float4*)&r_s[v][e8];
      float4 A = rp[0], Bv = rp[1];
      acc[0] += w * A.x;  acc[1] += w * A.y;  acc[2] += w * A.z;  acc[3] += w * A.w;
      acc[4] += w * Bv.x; acc[5] += w * Bv.y; acc[6] += w * Bv.z; acc[7] += w * Bv.w;
    }
  }
#pragma unroll
  for (int j = 0; j < 8; ++j) atomicAdd(&du[b * EDIM + e8 + j], acc[j]);
}

// ---------- k_lfin: final logits -> masked sigmoid ----------
__global__ void __launch_bounds__(256) k_lfin(const int* __restrict__ story,
                                              const float* __restrict__ Dt,
                                              const int* __restrict__ lengths,
                                              float* __restrict__ out) {
  const int bid = blockIdx.x, tid = threadIdx.x;
  const int b = bid >> 3, sl = bid & 7;
  const int s = sl * 256 + tid;
  int4 tk = ((const int4*)story)[b * SN + s];
  float l = Dt[(size_t)tk.x * 16 + b] + Dt[(size_t)tk.y * 16 + b]
          + Dt[(size_t)tk.z * 16 + b] + Dt[(size_t)tk.w * 16 + b];
  int len = lengths[b];
  out[134464 + (size_t)b * SN + s] = (s < len) ? 1.0f / (1.0f + expf(-l)) : 0.0f;
}

extern "C" void kernel_launch(void* const* d_in, const int* in_sizes, int n_in,
                              void* d_out, int out_size, void* d_ws, size_t ws_size,
                              hipStream_t stream) {
  const int *story = nullptr, *lengths = nullptr;
  const float *hidden = nullptr, *C = nullptr, *Wm = nullptr, *Wb = nullptr,
              *W1w = nullptr, *W1b = nullptr, *W3w = nullptr, *W3b = nullptr,
              *W4w = nullptr, *W4b = nullptr;
  for (int i = 0; i < n_in; ++i) {
    switch (in_sizes[i]) {
      case 16 * 2048 * 4:    story   = (const int*)d_in[i]; break;
      case 16:               lengths = (const int*)d_in[i]; break;
      case 16 * 128:         hidden  = (const float*)d_in[i]; break;
      case 4 * 100000 * 128: C       = (const float*)d_in[i]; break;
      case 128 * 128:        Wm      = (const float*)d_in[i]; break;
      case 128:              Wb      = (const float*)d_in[i]; break;
      case 2 * 128:          W1w     = (const float*)d_in[i]; break;
      case 2:                W1b     = (const float*)d_in[i]; break;
      case 4000 * 128:       W3w     = (const float*)d_in[i]; break;
      case 4000:             W3b     = (const float*)d_in[i]; break;
      case 200 * 128:        W4w     = (const float*)d_in[i]; break;
      case 200:              W4b     = (const float*)d_in[i]; break;
      default: break;
    }
  }
  float* out = (float*)d_out;
  float* ws  = (float*)d_ws;
  float* h   = ws + H_OFF;
  float* u0  = ws + U0_OFF;
  float* u1  = ws + U1_OFF;
  float* du  = ws + DU_OFF;      // [2][16][128]
  float* ps  = ws + PS_OFF;      // [16][8]
  float* pbv = ws + PBV_OFF;
  int*   pbi = (int*)(ws + PBI_OFF);
  float* Dt  = ws + DT_OFF;      // [100000][16]
  float* wt  = ws + WT_OFF;      // [100000][16]

  const float* C0 = C;
  const float* C1 = C + (size_t)1 * VOCABN * EDIM;
  const float* C2 = C + (size_t)2 * VOCABN * EDIM;

  uint32_t k0a, k0b, k1a, k1b, k2a, k2b;
  tf2x32(0u, 42u, 0u, 0u, &k0a, &k0b);
  tf2x32(0u, 42u, 0u, 1u, &k1a, &k1b);
  tf2x32(0u, 42u, 0u, 2u, &k2a, &k2b);

  k_h<<<BN, 128, 0, stream>>>(hidden, Wm, Wb, h, u0);
  k_heads<<<432, 256, 0, stream>>>(h, W1w, W1b, W3w, W3b, W4w, W4b,
                                   out, pbv, pbi, k0a, k0b, k1a, k1b, k2a, k2b);
  k_onehot<<<263, 256, 0, stream>>>(pbv, pbi, out);

  // hop 0: D0 = C0 . u0 ; scatter exp(l0) -> wt ; du0 = wt-weighted sum of C1
  k_D<<<NBV, 256, 0, stream>>>(C0, u0, nullptr, nullptr, 0, nullptr, Dt, wt, du);
  k_lscat<<<128, 256, 0, stream>>>(story, Dt, wt, ps);
  k_du<<<NBV, 256, 0, stream>>>(C1, wt, du);
  // hop 1: u1 = u0 + du0/S0 ; D1 = C1 . u1 ; scatter exp(l1) ; du1 over C2
  k_D<<<NBV, 256, 0, stream>>>(C1, u0, du, ps, 1, u1, Dt, wt, nullptr);
  k_lscat<<<128, 256, 0, stream>>>(story, Dt, wt, ps);
  k_du<<<NBV, 256, 0, stream>>>(C2, wt, du + 2048);
  // hop 2: u2 = u1 + du1/S1 ; D2 = C2 . u2 ; final masked sigmoid
  k_D<<<NBV, 256, 0, stream>>>(C2, u1, du + 2048, ps, 1, nullptr, Dt, nullptr, nullptr);
  k_lfin<<<128, 256, 0, stream>>>(story, Dt, lengths, out);
}

// Round 3
// 450.758 us; speedup vs baseline: 1.5922x; 1.5922x over previous
//
#include <hip/hip_runtime.h>
#include <hip/hip_bf16.h>
#include <stdint.h>

typedef __hip_bfloat16 bf16;
typedef __attribute__((ext_vector_type(8))) short bf16x8;
typedef __attribute__((ext_vector_type(4))) float f32x4;

#define VOCABN 100000
#define EDIM 128
#define BN 16
#define SN 2048

#define NB_D    625      // k_D blocks (4 waves each -> 2500 waves; 6250 tiles of 16 rows)
#define NB_DU   512      // k_du blocks
#define ROWS_PB 196      // rows per k_du block (512*196 = 100352 >= 100000)

// ws float offsets (end = 4,264,960 floats = 17.06 MB, <= round-1-proven 17.07 MB)
#define H_OFF    0        // 2048
#define U0_OFF   2048     // 2048
#define U1_OFF   4096     // 2048
#define U2_OFF   6144     // 2048
#define PS_OFF   8192     // 128  (psum[16][8])
#define PBV_OFF  8320     // 1200
#define PBI_OFF  9520     // 1200
#define DT_OFF   16384    // 1,600,000 (D^T [100000][16])
#define WT_OFF   1616384  // 1,600,000 (wt  [100000][16])
#define DUP_OFF  3216384  // 512*2048 = 1,048,576 (du partials)

// ---------- threefry2x32 (JAX partitionable) ----------
__host__ __device__ inline void tf2x32(uint32_t k0, uint32_t k1,
                                       uint32_t x0, uint32_t x1,
                                       uint32_t* o0, uint32_t* o1) {
  const uint32_t rotA[4] = {13u, 15u, 26u, 6u};
  const uint32_t rotB[4] = {17u, 29u, 16u, 24u};
  uint32_t ks0 = k0, ks1 = k1, ks2 = k0 ^ k1 ^ 0x1BD11BDAu;
  x0 += ks0; x1 += ks1;
#pragma unroll
  for (int g = 0; g < 5; ++g) {
    const uint32_t* r = (g & 1) ? rotB : rotA;
#pragma unroll
    for (int i = 0; i < 4; ++i) {
      x0 += x1;
      x1 = (x1 << r[i]) | (x1 >> (32u - r[i]));
      x1 ^= x0;
    }
    uint32_t a0 = (g % 3 == 0) ? ks1 : ((g % 3 == 1) ? ks2 : ks0);
    uint32_t a1 = (g % 3 == 0) ? ks2 : ((g % 3 == 1) ? ks0 : ks1);
    x0 += a0;
    x1 += a1 + (uint32_t)(g + 1);
  }
  *o0 = x0; *o1 = x1;
}

__device__ inline uint16_t f2bu(float f) {
  bf16 h = __float2bfloat16(f);
  uint16_t u; __builtin_memcpy(&u, &h, 2); return u;
}
__device__ inline float gumbel(uint32_t ka, uint32_t kb, uint32_t flat) {
  uint32_t o0, o1;
  tf2x32(ka, kb, 0u, flat, &o0, &o1);
  uint32_t bits = o0 ^ o1;
  float u0 = __uint_as_float((bits >> 9) | 0x3f800000u) - 1.0f;
  float uu = fmaxf(1e-10f, u0 + 1e-10f);
  return -logf(-logf(uu));
}

// ---------- h = hidden @ Wm^T + Wb ; u0 = h ----------
__global__ void k_h(const float* __restrict__ hidden, const float* __restrict__ Wm,
                    const float* __restrict__ Wb, float* __restrict__ h,
                    float* __restrict__ u) {
  int b = blockIdx.x, j = threadIdx.x;
  const float4* wr = (const float4*)(Wm + (size_t)j * EDIM);
  const float4* hr = (const float4*)(hidden + (size_t)b * EDIM);
  float acc = Wb[j];
#pragma unroll
  for (int i = 0; i < 32; ++i) {
    float4 w4 = wr[i], h4 = hr[i];
    acc += w4.x * h4.x + w4.y * h4.y + w4.z * h4.z + w4.w * h4.w;
  }
  h[b * EDIM + j] = acc;
  u[b * EDIM + j] = acc;
}

// ---------- heads: logits to out; per-chunk gumbel-argmax partials ----------
__global__ void k_heads(const float* __restrict__ h,
                        const float* __restrict__ W1w, const float* __restrict__ W1b,
                        const float* __restrict__ W3w, const float* __restrict__ W3b,
                        const float* __restrict__ W4w, const float* __restrict__ W4b,
                        float* __restrict__ out, float* __restrict__ pbv,
                        int* __restrict__ pbi,
                        uint32_t k0a, uint32_t k0b, uint32_t k1a, uint32_t k1b,
                        uint32_t k2a, uint32_t k2b) {
  int bid = blockIdx.x, tid = threadIdx.x;
  __shared__ float hb[EDIM];
  __shared__ float sv[256];
  __shared__ int si[256];
  int head, b2, base, cnt, chunk, N;
  const float *W, *bias; size_t lg_off; uint32_t ka, kb;
  if (bid < 400)      { head = 1; b2 = bid / 25; chunk = bid % 25; base = chunk * 160; cnt = 160;
                        W = W3w; bias = W3b; N = 4000; lg_off = 64;     ka = k1a; kb = k1b; }
  else if (bid < 416) { head = 2; b2 = bid - 400; chunk = 0; base = 0; cnt = 200;
                        W = W4w; bias = W4b; N = 200;  lg_off = 128064; ka = k2a; kb = k2b; }
  else                { head = 0; b2 = bid - 416; chunk = 0; base = 0; cnt = 2;
                        W = W1w; bias = W1b; N = 2;    lg_off = 0;      ka = k0a; kb = k0b; }
  if (tid < 128) hb[tid] = h[b2 * EDIM + tid];
  __syncthreads();
  float best = -INFINITY; int bi = 0x7FFFFFFF;
  if (tid < cnt) {
    int c = base + tid;
    const float4* wr = (const float4*)(W + (size_t)c * EDIM);
    const float4* hb4 = (const float4*)hb;
    float acc = bias[c];
#pragma unroll
    for (int i = 0; i < 32; ++i) {
      float4 w4 = wr[i], h4 = hb4[i];
      acc += w4.x * h4.x + w4.y * h4.y + w4.z * h4.z + w4.w * h4.w;
    }
    out[lg_off + (size_t)b2 * N + c] = acc;
    best = acc + gumbel(ka, kb, (uint32_t)(b2 * N + c));
    bi = c;
  }
  sv[tid] = best; si[tid] = bi;
  __syncthreads();
  for (int s2 = 128; s2 > 0; s2 >>= 1) {
    if (tid < s2) {
      float ov = sv[tid + s2]; int oi = si[tid + s2];
      if (ov > sv[tid] || (ov == sv[tid] && oi < si[tid])) { sv[tid] = ov; si[tid] = oi; }
    }
    __syncthreads();
  }
  if (tid == 0) {
    pbv[(head * 16 + b2) * 25 + chunk] = sv[0];
    pbi[(head * 16 + b2) * 25 + chunk] = si[0];
  }
}

// ---------- one-hots ----------
__global__ void k_onehot(const float* __restrict__ pbv, const int* __restrict__ pbi,
                         float* __restrict__ out) {
  int g = blockIdx.x * 256 + threadIdx.x;
  if (g >= 67232) return;
  int head, b2, c; size_t off; int nch;
  if (g < 64000)      { head = 1; b2 = g / 4000; c = g % 4000; off = 64064 + g;          nch = 25; }
  else if (g < 67200) { int gg = g - 64000; head = 2; b2 = gg / 200; c = gg % 200; off = 131264 + gg; nch = 1; }
  else                { int gg = g - 67200; head = 0; b2 = gg >> 1; c = gg & 1;   off = 32 + gg;     nch = 1; }
  float bv = -INFINITY; int bi = 0x7FFFFFFF;
  for (int ch = 0; ch < nch; ++ch) {
    float v = pbv[(head * 16 + b2) * 25 + ch];
    int i2 = pbi[(head * 16 + b2) * 25 + ch];
    if (v > bv || (v == bv && i2 < bi)) { bv = v; bi = i2; }
  }
  out[off] = (c == bi) ? 1.0f : 0.0f;
}

// ---------- k_D (MFMA): Dt[v][b] = Ct[v] . u[b] ----------
// 16-row tiles, A = bf16(Ct rows), B = bf16-split(u): acc = A*Bhi + A*Blo.
// Fragment scheme = guide-verified m97 pattern:
//   A: row=lane&15, k=(lane>>4)*8+i ; B: n=lane&15, k=(lane>>4)*8+i (u row-major)
//   D: n=lane&15, m=(lane>>4)*4+j
__global__ void __launch_bounds__(256) k_D(const float* __restrict__ Ct,
                                           const float* __restrict__ ub,
                                           float* __restrict__ Dt,
                                           float* __restrict__ wtz) {
  const int tid = threadIdx.x, bid = blockIdx.x;
  const int lane = tid & 63, w = tid >> 6;
  const int n = lane & 15, q = lane >> 4;
  if (wtz) {
    for (int i = bid * 256 + tid; i < VOCABN * 16; i += NB_D * 256) wtz[i] = 0.f;
  }
  // u fragments: hi + residual-lo bf16 pair (keeps u at ~16-bit mantissa)
  bf16x8 Bhi[4], Blo[4];
#pragma unroll
  for (int kk = 0; kk < 4; ++kk) {
    const float* up = ub + n * EDIM + kk * 32 + q * 8;
    float4 x0 = *(const float4*)up, x1 = *(const float4*)(up + 4);
    float xs[8] = {x0.x, x0.y, x0.z, x0.w, x1.x, x1.y, x1.z, x1.w};
#pragma unroll
    for (int i = 0; i < 8; ++i) {
      uint16_t hb = f2bu(xs[i]);
      float hf = __uint_as_float((uint32_t)hb << 16);
      Bhi[kk][i] = (short)hb;
      Blo[kk][i] = (short)f2bu(xs[i] - hf);
    }
  }
  for (int t = bid * 4 + w; t < VOCABN / 16; t += NB_D * 4) {
    const int v0 = t * 16;
    f32x4 acc = {0.f, 0.f, 0.f, 0.f};
#pragma unroll
    for (int kk = 0; kk < 4; ++kk) {
      const float* ap = Ct + (size_t)(v0 + n) * EDIM + kk * 32 + q * 8;
      float4 a0 = *(const float4*)ap, a1 = *(const float4*)(ap + 4);
      bf16x8 A;
      A[0] = (short)f2bu(a0.x); A[1] = (short)f2bu(a0.y);
      A[2] = (short)f2bu(a0.z); A[3] = (short)f2bu(a0.w);
      A[4] = (short)f2bu(a1.x); A[5] = (short)f2bu(a1.y);
      A[6] = (short)f2bu(a1.z); A[7] = (short)f2bu(a1.w);
      acc = __builtin_amdgcn_mfma_f32_16x16x32_bf16(A, Bhi[kk], acc, 0, 0, 0);
      acc = __builtin_amdgcn_mfma_f32_16x16x32_bf16(A, Blo[kk], acc, 0, 0, 0);
    }
#pragma unroll
    for (int j = 0; j < 4; ++j)
      Dt[(size_t)(v0 + q * 4 + j) * 16 + n] = acc[j];
  }
}

// ---------- k_lscat: l[b,s] = sum_m Dt[tok][b]; scatter exp(l) into wt; psum ----------
__global__ void __launch_bounds__(256) k_lscat(const int* __restrict__ story,
                                               const float* __restrict__ Dt,
                                               float* __restrict__ wt,
                                               float* __restrict__ ps) {
  const int bid = blockIdx.x, tid = threadIdx.x;
  const int b = bid >> 3, sl = bid & 7;
  const int s = sl * 256 + tid;
  const int wave = tid >> 6, lane = tid & 63;
  int4 tk = ((const int4*)story)[b * SN + s];
  float l = Dt[(size_t)tk.x * 16 + b] + Dt[(size_t)tk.y * 16 + b]
          + Dt[(size_t)tk.z * 16 + b] + Dt[(size_t)tk.w * 16 + b];
  float e = expf(l);
  atomicAdd(&wt[(size_t)tk.x * 16 + b], e);
  atomicAdd(&wt[(size_t)tk.y * 16 + b], e);
  atomicAdd(&wt[(size_t)tk.z * 16 + b], e);
  atomicAdd(&wt[(size_t)tk.w * 16 + b], e);
  float sum = e;
#pragma unroll
  for (int off = 32; off > 0; off >>= 1) sum += __shfl_xor(sum, off, 64);
  __shared__ float red[4];
  if (lane == 0) red[wave] = sum;
  __syncthreads();
  if (tid == 0) ps[b * 8 + sl] = red[0] + red[1] + red[2] + red[3];
}

// ---------- k_du: outer-product GEMV, no atomics ----------
// thread owns column-pair (lane*2) x all 16 b; wt row is a 64B broadcast.
// Block partials -> dup[bid][2048] (b-major), summed later by k_red.
__global__ void __launch_bounds__(256) k_du(const float* __restrict__ Ct,
                                            const float* __restrict__ wt,
                                            float* __restrict__ dup) {
  const int tid = threadIdx.x, bid = blockIdx.x;
  const int lane = tid & 63, w = tid >> 6;
  __shared__ float lds[3 * 64 * 33];   // +1 pad per lane-row: conflict-free
  float2 acc[16];
#pragma unroll
  for (int b = 0; b < 16; ++b) acc[b] = make_float2(0.f, 0.f);
  const int v0 = bid * ROWS_PB + w * (ROWS_PB / 4);
  int rows = ROWS_PB / 4;
  if (v0 + rows > VOCABN) rows = VOCABN - v0;   // may be <=0 -> loop skipped
  for (int r = 0; r < rows; ++r) {
    const int v = v0 + r;
    float2 cc = *(const float2*)(Ct + (size_t)v * EDIM + lane * 2);
    const float4* wp = (const float4*)(wt + (size_t)v * 16);
    float4 w0 = wp[0], w1 = wp[1], w2 = wp[2], w3 = wp[3];
    float wv[16] = {w0.x, w0.y, w0.z, w0.w, w1.x, w1.y, w1.z, w1.w,
                    w2.x, w2.y, w2.z, w2.w, w3.x, w3.y, w3.z, w3.w};
#pragma unroll
    for (int b = 0; b < 16; ++b) {
      acc[b].x += wv[b] * cc.x;
      acc[b].y += wv[b] * cc.y;
    }
  }
  if (w > 0) {
    float* p = lds + (w - 1) * (64 * 33) + lane * 33;
#pragma unroll
    for (int b = 0; b < 16; ++b) { p[b * 2] = acc[b].x; p[b * 2 + 1] = acc[b].y; }
  }
  __syncthreads();
  if (w == 0) {
#pragma unroll
    for (int b = 0; b < 16; ++b) {
      float ax = acc[b].x, ay = acc[b].y;
#pragma unroll
      for (int s = 0; s < 3; ++s) {
        const float* p = lds + s * (64 * 33) + lane * 33;
        ax += p[b * 2]; ay += p[b * 2 + 1];
      }
      *(float2*)(dup + (size_t)bid * 2048 + b * EDIM + lane * 2) = make_float2(ax, ay);
    }
  }
}

// ---------- k_red: u_next = u_prev + (sum_p dup[p]) / S_b ----------
__global__ void __launch_bounds__(256) k_red(const float* __restrict__ dup,
                                             const float* __restrict__ ps,
                                             const float* __restrict__ u_prev,
                                             float* __restrict__ u_next) {
  const int o = blockIdx.x * 256 + threadIdx.x;   // 0..2047 (grid 8)
  float s = 0.f;
  for (int p = 0; p < NB_DU; ++p) s += dup[(size_t)p * 2048 + o];
  const int b = o >> 7;
  float S = 0.f;
#pragma unroll
  for (int i = 0; i < 8; ++i) S += ps[b * 8 + i];
  u_next[o] = u_prev[o] + s / S;
}

// ---------- k_lfin: final logits -> masked sigmoid ----------
__global__ void __launch_bounds__(256) k_lfin(const int* __restrict__ story,
                                              const float* __restrict__ Dt,
                                              const int* __restrict__ lengths,
                                              float* __restrict__ out) {
  const int bid = blockIdx.x, tid = threadIdx.x;
  const int b = bid >> 3, sl = bid & 7;
  const int s = sl * 256 + tid;
  int4 tk = ((const int4*)story)[b * SN + s];
  float l = Dt[(size_t)tk.x * 16 + b] + Dt[(size_t)tk.y * 16 + b]
          + Dt[(size_t)tk.z * 16 + b] + Dt[(size_t)tk.w * 16 + b];
  int len = lengths[b];
  out[134464 + (size_t)b * SN + s] = (s < len) ? 1.0f / (1.0f + expf(-l)) : 0.0f;
}

extern "C" void kernel_launch(void* const* d_in, const int* in_sizes, int n_in,
                              void* d_out, int out_size, void* d_ws, size_t ws_size,
                              hipStream_t stream) {
  const int *story = nullptr, *lengths = nullptr;
  const float *hidden = nullptr, *C = nullptr, *Wm = nullptr, *Wb = nullptr,
              *W1w = nullptr, *W1b = nullptr, *W3w = nullptr, *W3b = nullptr,
              *W4w = nullptr, *W4b = nullptr;
  for (int i = 0; i < n_in; ++i) {
    switch (in_sizes[i]) {
      case 16 * 2048 * 4:    story   = (const int*)d_in[i]; break;
      case 16:               lengths = (const int*)d_in[i]; break;
      case 16 * 128:         hidden  = (const float*)d_in[i]; break;
      case 4 * 100000 * 128: C       = (const float*)d_in[i]; break;
      case 128 * 128:        Wm      = (const float*)d_in[i]; break;
      case 128:              Wb      = (const float*)d_in[i]; break;
      case 2 * 128:          W1w     = (const float*)d_in[i]; break;
      case 2:                W1b     = (const float*)d_in[i]; break;
      case 4000 * 128:       W3w     = (const float*)d_in[i]; break;
      case 4000:             W3b     = (const float*)d_in[i]; break;
      case 200 * 128:        W4w     = (const float*)d_in[i]; break;
      case 200:              W4b     = (const float*)d_in[i]; break;
      default: break;
    }
  }
  float* out = (float*)d_out;
  float* ws  = (float*)d_ws;
  float* h   = ws + H_OFF;
  float* u0  = ws + U0_OFF;
  float* u1  = ws + U1_OFF;
  float* u2  = ws + U2_OFF;
  float* ps  = ws + PS_OFF;
  float* pbv = ws + PBV_OFF;
  int*   pbi = (int*)(ws + PBI_OFF);
  float* Dt  = ws + DT_OFF;
  float* wt  = ws + WT_OFF;
  float* dup = ws + DUP_OFF;

  const float* C0 = C;
  const float* C1 = C + (size_t)1 * VOCABN * EDIM;
  const float* C2 = C + (size_t)2 * VOCABN * EDIM;

  uint32_t k0a, k0b, k1a, k1b, k2a, k2b;
  tf2x32(0u, 42u, 0u, 0u, &k0a, &k0b);
  tf2x32(0u, 42u, 0u, 1u, &k1a, &k1b);
  tf2x32(0u, 42u, 0u, 2u, &k2a, &k2b);

  k_h<<<BN, 128, 0, stream>>>(hidden, Wm, Wb, h, u0);
  k_heads<<<432, 256, 0, stream>>>(h, W1w, W1b, W3w, W3b, W4w, W4b,
                                   out, pbv, pbi, k0a, k0b, k1a, k1b, k2a, k2b);
  k_onehot<<<263, 256, 0, stream>>>(pbv, pbi, out);

  // hop 0
  k_D<<<NB_D, 256, 0, stream>>>(C0, u0, Dt, wt);
  k_lscat<<<128, 256, 0, stream>>>(story, Dt, wt, ps);
  k_du<<<NB_DU, 256, 0, stream>>>(C1, wt, dup);
  k_red<<<8, 256, 0, stream>>>(dup, ps, u0, u1);
  // hop 1
  k_D<<<NB_D, 256, 0, stream>>>(C1, u1, Dt, wt);
  k_lscat<<<128, 256, 0, stream>>>(story, Dt, wt, ps);
  k_du<<<NB_DU, 256, 0, stream>>>(C2, wt, dup);
  k_red<<<8, 256, 0, stream>>>(dup, ps, u1, u2);
  // hop 2: final logits -> masked sigmoid
  k_D<<<NB_D, 256, 0, stream>>>(C2, u2, Dt, nullptr);
  k_lfin<<<128, 256, 0, stream>>>(story, Dt, lengths, out);
}